// Round 2
// baseline (158.515 us; speedup 1.0000x reference)
//
#include <hip/hip_runtime.h>
#include <math.h>

#define DD 160
#define HH 160
#define WW 160
#define NB 2
#define SLICE (HH * WW)        // 25600
#define NV 51200               // NB*160*160 vectors per reduction type
#define Dt 4                   // d's per gradH block
#define NDC 40                 // d-chunks (160/Dt)
#define NHC 10                 // h-chunks
#define HCS 16                 // rows per h-chunk
#define NTHR 320               // 8 groups x 40 float4-lanes
#define DQ 4                   // gradD d-quarters -> alongD partial chunks
#define DPG 5                  // d's per group in gradD = (DD/DQ)/8

static constexpr float EPS = 1e-12f;
static constexpr float SCALE = -1.0f / 960.0f;  // -(six cos sums)/(160*2*3)

#define ELEM(v, j) ((j) == 0 ? (v).x : ((j) == 1 ? (v).y : ((j) == 2 ? (v).z : (v).w)))

__global__ void zero_kernel(float* out) {
  if (threadIdx.x == 0) out[0] = 0.0f;
}

// ---------------------------------------------------------------------------
// gradH: alongW (complete, -> accCos) + alongH partials (gx,gz) -> pH[10][6][NV].
// Same block shape as before (b, 4d, 16h, full W) with register chain along D,
// but alongD work removed (now in gradD) and the d-neighbor slice loads
// software-prefetched one phase ahead: they are issued before phase p's
// compute + 2 barriers, hiding their latency instead of stalling on them.
// ---------------------------------------------------------------------------
__global__ __launch_bounds__(NTHR, 2) void gradH(const float* __restrict__ f,
                                                 const float* __restrict__ t,
                                                 float* __restrict__ pH,
                                                 float* __restrict__ out) {
  __shared__ float sw[HCS * 40 * 7];    // per-(row,lane) alongW partials
  __shared__ float sh[8 * 40 * 25];     // per-(group,lane) alongH partials
  __shared__ float red[HCS][6];
  __shared__ float cpad[HCS];
  const int tid = threadIdx.x;
  const int g = tid / 40;               // group 0..7
  const int l = tid % 40;               // float4-lane
  const int w = 4 * l;
  const int wn = (w + 4 < WW) ? (w + 4) : (WW - 1);  // clamp -> gz[3]=0 at w=159
  const int hc = blockIdx.x % NHC;
  const int t2 = blockIdx.x / NHC;
  const int dc = t2 % NDC;
  const int b  = t2 / NDC;
  const int d0 = dc * Dt;
  const int r0 = hc * HCS + g * 2;      // thread's two consecutive rows
  const int r1 = r0 + 1;
  const int r2 = (r1 + 1 < HH) ? (r1 + 1) : (HH - 1);  // clamp -> gy=0 at h=159
  const float* fb = f + (size_t)b * DD * SLICE;
  const float* tb = t + (size_t)b * DD * SLICE;

  // chain selves: slice d0, rows r0,r1 (+ wn scalars)
  float4 S0f = *(const float4*)(fb + (size_t)d0 * SLICE + r0 * WW + w);
  float4 S0t = *(const float4*)(tb + (size_t)d0 * SLICE + r0 * WW + w);
  float4 S1f = *(const float4*)(fb + (size_t)d0 * SLICE + r1 * WW + w);
  float4 S1t = *(const float4*)(tb + (size_t)d0 * SLICE + r1 * WW + w);
  float s0fz = (fb + (size_t)d0 * SLICE + r0 * WW)[wn];
  float s0tz = (tb + (size_t)d0 * SLICE + r0 * WW)[wn];
  float s1fz = (fb + (size_t)d0 * SLICE + r1 * WW)[wn];
  float s1tz = (tb + (size_t)d0 * SLICE + r1 * WW)[wn];
  // prefetched d-neighbor slice d0+1 (d0 <= 156, always in range)
  const float* fN0 = fb + (size_t)(d0 + 1) * SLICE;
  const float* tN0 = tb + (size_t)(d0 + 1) * SLICE;
  float4 D0f = *(const float4*)(fN0 + r0 * WW + w);
  float4 D0t = *(const float4*)(tN0 + r0 * WW + w);
  float4 D1f = *(const float4*)(fN0 + r1 * WW + w);
  float4 D1t = *(const float4*)(tN0 + r1 * WW + w);
  float d0fz = (fN0 + r0 * WW)[wn], d0tz = (tN0 + r0 * WW)[wn];
  float d1fz = (fN0 + r1 * WW)[wn], d1tz = (tN0 + r1 * WW)[wn];

  float accCos = 0.0f;

#pragma unroll
  for (int p = 0; p < Dt; ++p) {
    const int d = d0 + p;
    const float* fS = fb + (size_t)d * SLICE;
    const float* tS = tb + (size_t)d * SLICE;
    // same-slice row r2 (L1/L2 hit: neighbor group loaded it last phase)
    const float4 Hf = *(const float4*)(fS + r2 * WW + w);
    const float4 Ht = *(const float4*)(tS + r2 * WW + w);
    // prefetch NEXT phase's d-neighbor slice (the cold loads)
    float4 nD0f = {0, 0, 0, 0}, nD0t = {0, 0, 0, 0};
    float4 nD1f = {0, 0, 0, 0}, nD1t = {0, 0, 0, 0};
    float n0fz = 0.f, n0tz = 0.f, n1fz = 0.f, n1tz = 0.f;
    if (p < Dt - 1) {
      const int nd = d + 1;
      const int ndn = (nd + 1 < DD) ? (nd + 1) : nd;  // clamp -> gx=0 at d=159
      const float* fN = fb + (size_t)ndn * SLICE;
      const float* tN = tb + (size_t)ndn * SLICE;
      nD0f = *(const float4*)(fN + r0 * WW + w);
      nD0t = *(const float4*)(tN + r0 * WW + w);
      nD1f = *(const float4*)(fN + r1 * WW + w);
      nD1t = *(const float4*)(tN + r1 * WW + w);
      n0fz = (fN + r0 * WW)[wn]; n0tz = (tN + r0 * WW)[wn];
      n1fz = (fN + r1 * WW)[wn]; n1tz = (tN + r1 * WW)[wn];
    }

    float aH[24];
#pragma unroll
    for (int c = 0; c < 24; ++c) aH[c] = 0.0f;

    // ---- row r0: gx = D0-S0, gy = S1-S0, gz = shift(S0) ----
    {
      float xd = 0, xf = 0, xt = 0, yd = 0, yf = 0, yt = 0;
#pragma unroll
      for (int j = 0; j < 4; ++j) {
        const float f0 = ELEM(S0f, j), t0 = ELEM(S0t, j);
        const float gxf = ELEM(D0f, j) - f0, gxt = ELEM(D0t, j) - t0;
        const float gyf = ELEM(S1f, j) - f0, gyt = ELEM(S1t, j) - t0;
        const float fnx = (j < 3) ? ELEM(S0f, j + 1) : s0fz;
        const float tnx = (j < 3) ? ELEM(S0t, j + 1) : s0tz;
        const float gzf = fnx - f0, gzt = tnx - t0;
        xd += gxf * gxt; xf += gxf * gxf; xt += gxt * gxt;
        yd += gyf * gyt; yf += gyf * gyf; yt += gyt * gyt;
        aH[j * 6 + 0] += gxf * gxt; aH[j * 6 + 1] += gxf * gxf; aH[j * 6 + 2] += gxt * gxt;
        aH[j * 6 + 3] += gzf * gzt; aH[j * 6 + 4] += gzf * gzf; aH[j * 6 + 5] += gzt * gzt;
      }
      float* s = &sw[((g * 2 + 0) * 40 + l) * 7];
      s[0] = xd; s[1] = xf; s[2] = xt; s[3] = yd; s[4] = yf; s[5] = yt;
    }
    // ---- row r1: gx = D1-S1, gy = H-S1, gz = shift(S1) ----
    {
      float xd = 0, xf = 0, xt = 0, yd = 0, yf = 0, yt = 0;
#pragma unroll
      for (int j = 0; j < 4; ++j) {
        const float f0 = ELEM(S1f, j), t0 = ELEM(S1t, j);
        const float gxf = ELEM(D1f, j) - f0, gxt = ELEM(D1t, j) - t0;
        const float gyf = ELEM(Hf, j) - f0, gyt = ELEM(Ht, j) - t0;
        const float fnx = (j < 3) ? ELEM(S1f, j + 1) : s1fz;
        const float tnx = (j < 3) ? ELEM(S1t, j + 1) : s1tz;
        const float gzf = fnx - f0, gzt = tnx - t0;
        xd += gxf * gxt; xf += gxf * gxf; xt += gxt * gxt;
        yd += gyf * gyt; yf += gyf * gyf; yt += gyt * gyt;
        aH[j * 6 + 0] += gxf * gxt; aH[j * 6 + 1] += gxf * gxf; aH[j * 6 + 2] += gxt * gxt;
        aH[j * 6 + 3] += gzf * gzt; aH[j * 6 + 4] += gzf * gzf; aH[j * 6 + 5] += gzt * gzt;
      }
      float* s = &sw[((g * 2 + 1) * 40 + l) * 7];
      s[0] = xd; s[1] = xf; s[2] = xt; s[3] = yd; s[4] = yf; s[5] = yt;
    }
    // dump alongH partials
    {
      float* s2 = &sh[(g * 40 + l) * 25];
#pragma unroll
      for (int c = 0; c < 24; ++c) s2[c] = aH[c];
    }
    // register chain: next selves = this phase's d-neighbors; D <- prefetched
    S0f = D0f; S0t = D0t; S1f = D1f; S1t = D1t;
    s0fz = d0fz; s0tz = d0tz; s1fz = d1fz; s1tz = d1tz;
    if (p < Dt - 1) {
      D0f = nD0f; D0t = nD0t; D1f = nD1f; D1t = nD1t;
      d0fz = n0fz; d0tz = n0tz; d1fz = n1fz; d1tz = n1tz;
    }
    __syncthreads();

    if (tid < 240) {
      // alongH reduce over 8 groups + coalesced f4 write to pH
      const int cc = tid / 40, ll = tid % 40;
      float v0 = 0, v1 = 0, v2 = 0, v3 = 0;
#pragma unroll
      for (int gg = 0; gg < 8; ++gg) {
        const float* q = &sh[(gg * 40 + ll) * 25];
        v0 += q[0 * 6 + cc]; v1 += q[1 * 6 + cc]; v2 += q[2 * 6 + cc]; v3 += q[3 * 6 + cc];
      }
      const int bd = b * DD + d;
      float4 o; o.x = v0; o.y = v1; o.z = v2; o.w = v3;
      *(float4*)(pH + ((size_t)(hc * 6 + cc)) * NV + bd * 160 + 4 * ll) = o;
    } else {
      // alongW reduce over 40 lanes: 96 tasks on 80 threads
      for (int k = tid - 240; k < HCS * 6; k += 80) {
        const int row = k / 6, c = k % 6;
        float s = 0.0f;
#pragma unroll 8
        for (int ll = 0; ll < 40; ++ll) s += sw[(row * 40 + ll) * 7 + c];
        red[row][c] = s;
      }
    }
    __syncthreads();
    if (tid < HCS) {
      const float cx = red[tid][0] / (fmaxf(sqrtf(red[tid][1]), EPS) * fmaxf(sqrtf(red[tid][2]), EPS));
      const float cy = red[tid][3] / (fmaxf(sqrtf(red[tid][4]), EPS) * fmaxf(sqrtf(red[tid][5]), EPS));
      accCos += cx + cy;
    }
  }

  if (tid < HCS) cpad[tid] = accCos;
  __syncthreads();
  if (tid == 0) {
    float s = 0.0f;
#pragma unroll
    for (int i = 0; i < HCS; ++i) s += cpad[i];
    atomicAdd(out, s * SCALE);
  }
}

// ---------------------------------------------------------------------------
// gradD: alongD partials (gy,gz) with deep d-coverage. Block = (b, h, dq):
// 8 groups each own 5 consecutive d's of a 40-deep quarter, one row h, full W.
// gy = f[d,h+1,w]-f[d,h,w] (clamped 0 at h=159), gz = shift-w. No d-neighbor
// needed -> 30 fully independent loads per thread (deep MLP). Group partials
// combined in LDS, then one coalesced f4 write per comp -> pD[4][6][NV].
// The 49 MB alongD partial array becomes 4.9 MB.
// ---------------------------------------------------------------------------
__global__ __launch_bounds__(NTHR, 2) void gradD(const float* __restrict__ f,
                                                 const float* __restrict__ t,
                                                 float* __restrict__ pD) {
  __shared__ float sh[8 * 40 * 25];
  const int tid = threadIdx.x;
  const int g = tid / 40;
  const int l = tid % 40;
  const int w = 4 * l;
  const int wn = (w + 4 < WW) ? (w + 4) : (WW - 1);  // clamp -> gz[3]=0 at w=159
  const int dq = blockIdx.x % DQ;
  const int t2 = blockIdx.x / DQ;
  const int h = t2 % HH;
  const int b = t2 / HH;
  const int hn = (h + 1 < HH) ? (h + 1) : h;          // clamp -> gy=0 at h=159
  const float* rowF  = f + (size_t)b * DD * SLICE + h * WW;
  const float* rowT  = t + (size_t)b * DD * SLICE + h * WW;
  const float* rowFn = f + (size_t)b * DD * SLICE + hn * WW;
  const float* rowTn = t + (size_t)b * DD * SLICE + hn * WW;
  const int dbeg = dq * (DD / DQ) + g * DPG;

  float a[24];
#pragma unroll
  for (int c = 0; c < 24; ++c) a[c] = 0.0f;

#pragma unroll
  for (int i = 0; i < DPG; ++i) {
    const size_t off = (size_t)(dbeg + i) * SLICE;
    const float4 Sf = *(const float4*)(rowF + off + w);
    const float4 St = *(const float4*)(rowT + off + w);
    const float4 Nf = *(const float4*)(rowFn + off + w);
    const float4 Nt = *(const float4*)(rowTn + off + w);
    const float sfz = (rowF + off)[wn];
    const float stz = (rowT + off)[wn];
#pragma unroll
    for (int j = 0; j < 4; ++j) {
      const float f0 = ELEM(Sf, j), t0 = ELEM(St, j);
      const float gyf = ELEM(Nf, j) - f0, gyt = ELEM(Nt, j) - t0;
      const float fnx = (j < 3) ? ELEM(Sf, j + 1) : sfz;
      const float tnx = (j < 3) ? ELEM(St, j + 1) : stz;
      const float gzf = fnx - f0, gzt = tnx - t0;
      a[j * 6 + 0] += gyf * gyt; a[j * 6 + 1] += gyf * gyf; a[j * 6 + 2] += gyt * gyt;
      a[j * 6 + 3] += gzf * gzt; a[j * 6 + 4] += gzf * gzf; a[j * 6 + 5] += gzt * gzt;
    }
  }
  {
    float* s2 = &sh[(g * 40 + l) * 25];
#pragma unroll
    for (int c = 0; c < 24; ++c) s2[c] = a[c];
  }
  __syncthreads();
  if (tid < 240) {
    const int cc = tid / 40, ll = tid % 40;
    float v0 = 0, v1 = 0, v2 = 0, v3 = 0;
#pragma unroll
    for (int gg = 0; gg < 8; ++gg) {
      const float* q = &sh[(gg * 40 + ll) * 25];
      v0 += q[0 * 6 + cc]; v1 += q[1 * 6 + cc]; v2 += q[2 * 6 + cc]; v3 += q[3 * 6 + cc];
    }
    float4 o; o.x = v0; o.y = v1; o.z = v2; o.w = v3;
    *(float4*)(pD + ((size_t)(dq * 6 + cc)) * NV + b * SLICE + h * 160 + 4 * ll) = o;
  }
}

// ---------------------------------------------------------------------------
// Combine chunk partials -> cosines -> loss.
// types: 0 gx-alongH, 1 gz-alongH (sum 10 hc); 2 gy-alongD, 3 gz-alongD (sum 4 dq).
// ---------------------------------------------------------------------------
__global__ __launch_bounds__(256) void finalize_kernel(const float* __restrict__ PH,
                                                       const float* __restrict__ PD,
                                                       float* __restrict__ out) {
  const int v = blockIdx.x * 256 + threadIdx.x;
  float c = 0.0f;
  if (v < 4 * NV) {
    const int type = v / NV;
    const int vec = v % NV;
    float dot = 0.0f, ff = 0.0f, tt = 0.0f;
    if (type < 2) {
      const float* base = PH + (size_t)(type * 3) * NV + vec;
#pragma unroll
      for (int ch = 0; ch < NHC; ++ch) {
        const float* q = base + (size_t)(ch * 6) * NV;
        dot += q[0]; ff += q[(size_t)NV]; tt += q[2 * (size_t)NV];
      }
    } else {
      const float* base = PD + (size_t)((type - 2) * 3) * NV + vec;
#pragma unroll
      for (int ch = 0; ch < DQ; ++ch) {
        const float* q = base + (size_t)(ch * 6) * NV;
        dot += q[0]; ff += q[(size_t)NV]; tt += q[2 * (size_t)NV];
      }
    }
    c = dot / (fmaxf(sqrtf(ff), EPS) * fmaxf(sqrtf(tt), EPS));
  }
#pragma unroll
  for (int m = 32; m >= 1; m >>= 1) c += __shfl_xor(c, m);
  __shared__ float part[4];
  if ((threadIdx.x & 63) == 0) part[threadIdx.x >> 6] = c;
  __syncthreads();
  if (threadIdx.x == 0) atomicAdd(out, (part[0] + part[1] + part[2] + part[3]) * SCALE);
}

extern "C" void kernel_launch(void* const* d_in, const int* in_sizes, int n_in,
                              void* d_out, int out_size, void* d_ws, size_t ws_size,
                              hipStream_t stream) {
  const float* fk = (const float*)d_in[0];
  const float* tr = (const float*)d_in[1];
  float* out = (float*)d_out;
  float* PH = (float*)d_ws;                         // [NHC][6][NV] = 12.3 MB
  float* PD = PH + (size_t)NHC * 6 * NV;            // [DQ][6][NV]  =  4.9 MB

  hipLaunchKernelGGL(zero_kernel, dim3(1), dim3(64), 0, stream, out);
  hipLaunchKernelGGL(gradH, dim3(NB * NDC * NHC), dim3(NTHR), 0, stream, fk, tr, PH, out);
  hipLaunchKernelGGL(gradD, dim3(NB * HH * DQ), dim3(NTHR), 0, stream, fk, tr, PD);
  hipLaunchKernelGGL(finalize_kernel, dim3((4 * NV + 255) / 256), dim3(256), 0, stream, PH, PD, out);
}